// Round 1
// baseline (9512.680 us; speedup 1.0000x reference)
//
#include <hip/hip_runtime.h>
#include <hip/hip_bf16.h>
#include <math.h>

// Swin Transformer block, B=64, H=W=56, C=96, heads=3, hd=32, win=7, shift=3
// Layout: windows per image NW=64 (8x8), tokens per window WW=49, MLP hidden 384.

#define BATCH 64
#define HH 56
#define WWID 56
#define CH 96
#define HEADS 3
#define HD 32
#define WIN 7
#define SHIFT 3
#define NW 64
#define TOK 49
#define MLPH 384
#define SCALE 0.17677669529663687f  // 1/sqrt(32)

// region label for shifted-window mask: [0,49)=0, [49,53)=1, [53,56)=2
__device__ __forceinline__ int region(int p) {
    return (p < HH - WIN) ? 0 : ((p < HH - SHIFT) ? 1 : 2);
}

__global__ __launch_bounds__(256) void swin_attn_kernel(
    const float* __restrict__ x,
    const float* __restrict__ n1w, const float* __restrict__ n1b,
    const float* __restrict__ qkvw, const float* __restrict__ qkvb,
    const float* __restrict__ relb,
    const float* __restrict__ projw, const float* __restrict__ projb,
    float* __restrict__ out)
{
    __shared__ float xln[TOK][97];      // LN'd window tokens (pad 97: kills stride-96 conflicts)
    __shared__ float qf[TOK][33];
    __shared__ float kf[TOK][33];
    __shared__ float vf[TOK][33];
    __shared__ float attn[25][49];      // q-half at a time (LDS budget)
    __shared__ float outacc[TOK][CH];   // attention output (head-concat), pre-proj
    __shared__ float stat[TOK][2];      // mu, rstd
    __shared__ int rowidx[TOK];         // token -> row index in [0, 3136)

    const int blk = blockIdx.x;
    const int b = blk >> 6;             // batch
    const int win = blk & 63;           // window in image
    const int wi = win >> 3, wj = win & 7;
    const int tid = threadIdx.x;

    if (tid < TOK) {
        int ti = tid / WIN, tj = tid - WIN * (tid / WIN);
        int ph = (wi * WIN + ti + SHIFT) % HH;   // inverse of roll(-3): gather from (s+3)%56
        int pw = (wj * WIN + tj + SHIFT) % WWID;
        rowidx[tid] = ph * WWID + pw;
    }
    __syncthreads();

    const float* xb = x + (size_t)b * (HH * WWID * CH);

    // load window tokens
    for (int idx = tid; idx < TOK * CH; idx += 256) {
        int r = idx / CH, c = idx - r * CH;
        xln[r][c] = xb[rowidx[r] * CH + c];
    }
    __syncthreads();

    // LN1 stats (one thread per token)
    if (tid < TOK) {
        float mu = 0.f;
        for (int c = 0; c < CH; ++c) mu += xln[tid][c];
        mu *= (1.f / CH);
        float var = 0.f;
        for (int c = 0; c < CH; ++c) { float d = xln[tid][c] - mu; var += d * d; }
        var *= (1.f / CH);
        stat[tid][0] = mu;
        stat[tid][1] = rsqrtf(var + 1e-5f);
    }
    __syncthreads();
    for (int idx = tid; idx < TOK * CH; idx += 256) {
        int r = idx / CH, c = idx - r * CH;
        xln[r][c] = (xln[r][c] - stat[r][0]) * stat[r][1] * n1w[c] + n1b[c];
    }
    __syncthreads();

    // per-head attention
    for (int h = 0; h < HEADS; ++h) {
        // qkv for this head: 3*49*32 = 4704 outputs, 96-MAC dot each
        for (int o = tid; o < 3 * TOK * HD; o += 256) {
            int which = o / (TOK * HD);
            int rem = o - which * (TOK * HD);
            int r = rem >> 5, d = rem & 31;
            int wrow = which * CH + h * HD + d;
            const float* wp = qkvw + wrow * CH;
            float acc = qkvb[wrow];
            #pragma unroll
            for (int c = 0; c < CH; c += 4) {
                acc += xln[r][c] * wp[c] + xln[r][c + 1] * wp[c + 1]
                     + xln[r][c + 2] * wp[c + 2] + xln[r][c + 3] * wp[c + 3];
            }
            if (which == 0)      qf[r][d] = acc * SCALE;
            else if (which == 1) kf[r][d] = acc;
            else                 vf[r][d] = acc;
        }
        __syncthreads();

        // attention in two q-halves (LDS budget for scores)
        for (int qh = 0; qh < 2; ++qh) {
            const int q0 = qh * 25;
            const int nq = qh ? 24 : 25;
            for (int o = tid; o < nq * TOK; o += 256) {
                int ql = o / TOK, kk = o - ql * TOK;
                int q = q0 + ql;
                float s = 0.f;
                #pragma unroll
                for (int d = 0; d < HD; ++d) s += qf[q][d] * kf[kk][d];
                int qhh = q / WIN, qww = q - WIN * qhh;
                int khh = kk / WIN, kww = kk - WIN * khh;
                int ridx = (qhh - khh + WIN - 1) * (2 * WIN - 1) + (qww - kww + WIN - 1);
                s += relb[ridx * HEADS + h];
                // shifted-window mask from region labels (shifted coords)
                int rq = region(wi * WIN + qhh) * 3 + region(wj * WIN + qww);
                int rk = region(wi * WIN + khh) * 3 + region(wj * WIN + kww);
                if (rq != rk) s -= 100.f;
                attn[ql][kk] = s;
            }
            __syncthreads();
            // softmax per row
            if (tid < nq) {
                float m = -1e30f;
                for (int kk = 0; kk < TOK; ++kk) m = fmaxf(m, attn[tid][kk]);
                float ssum = 0.f;
                for (int kk = 0; kk < TOK; ++kk) {
                    float e = expf(attn[tid][kk] - m);
                    attn[tid][kk] = e;
                    ssum += e;
                }
                float inv = 1.f / ssum;
                for (int kk = 0; kk < TOK; ++kk) attn[tid][kk] *= inv;
            }
            __syncthreads();
            // PV
            for (int o = tid; o < nq * HD; o += 256) {
                int ql = o >> 5, d = o & 31;
                float acc = 0.f;
                #pragma unroll
                for (int kk = 0; kk < TOK; ++kk) acc += attn[ql][kk] * vf[kk][d];
                outacc[q0 + ql][h * HD + d] = acc;
            }
            __syncthreads();
        }
    }

    // proj + residual + scatter (inverse shift)
    for (int o = tid; o < TOK * CH; o += 256) {
        int r = o / CH, c = o - r * CH;
        const float* wp = projw + c * CH;
        float acc = projb[c];
        #pragma unroll
        for (int m = 0; m < CH; m += 4) {
            acc += outacc[r][m] * wp[m] + outacc[r][m + 1] * wp[m + 1]
                 + outacc[r][m + 2] * wp[m + 2] + outacc[r][m + 3] * wp[m + 3];
        }
        size_t gi = (size_t)b * (HH * WWID * CH) + (size_t)rowidx[r] * CH + c;
        out[gi] = xb[rowidx[r] * CH + c] + acc;
    }
}

__global__ __launch_bounds__(256) void swin_mlp_kernel(
    float* __restrict__ io,
    const float* __restrict__ n2w, const float* __restrict__ n2b,
    const float* __restrict__ fc1w, const float* __restrict__ fc1b,
    const float* __restrict__ fc2w, const float* __restrict__ fc2b)
{
    __shared__ float xln[32][97];
    __shared__ float h2[32][MLPH];
    __shared__ float stat2[32][2];

    const int t0 = blockIdx.x * 32;   // token offset in [0, 200704)
    const int tid = threadIdx.x;

    for (int idx = tid; idx < 32 * CH; idx += 256) {
        int r = idx / CH, c = idx - r * CH;
        xln[r][c] = io[(size_t)(t0 + r) * CH + c];
    }
    __syncthreads();
    if (tid < 32) {
        float mu = 0.f;
        for (int c = 0; c < CH; ++c) mu += xln[tid][c];
        mu *= (1.f / CH);
        float var = 0.f;
        for (int c = 0; c < CH; ++c) { float d = xln[tid][c] - mu; var += d * d; }
        var *= (1.f / CH);
        stat2[tid][0] = mu;
        stat2[tid][1] = rsqrtf(var + 1e-5f);
    }
    __syncthreads();
    for (int idx = tid; idx < 32 * CH; idx += 256) {
        int r = idx / CH, c = idx - r * CH;
        xln[r][c] = (xln[r][c] - stat2[r][0]) * stat2[r][1] * n2w[c] + n2b[c];
    }
    __syncthreads();

    // fc1 + exact GELU
    for (int o = tid; o < 32 * MLPH; o += 256) {
        int r = o / MLPH, m = o - r * MLPH;
        const float* wp = fc1w + m * CH;
        float acc = fc1b[m];
        #pragma unroll
        for (int c = 0; c < CH; c += 4) {
            acc += xln[r][c] * wp[c] + xln[r][c + 1] * wp[c + 1]
                 + xln[r][c + 2] * wp[c + 2] + xln[r][c + 3] * wp[c + 3];
        }
        h2[r][m] = 0.5f * acc * (1.f + erff(acc * 0.70710678118654752f));
    }
    __syncthreads();

    // fc2 + residual (in-place read-modify-write; each element owned by one thread)
    for (int o = tid; o < 32 * CH; o += 256) {
        int r = o / CH, c = o - r * CH;
        const float* wp = fc2w + c * MLPH;
        float acc = fc2b[c];
        #pragma unroll 8
        for (int m = 0; m < MLPH; m += 4) {
            acc += h2[r][m] * wp[m] + h2[r][m + 1] * wp[m + 1]
                 + h2[r][m + 2] * wp[m + 2] + h2[r][m + 3] * wp[m + 3];
        }
        size_t gi = (size_t)(t0 + r) * CH + c;
        io[gi] = io[gi] + acc;
    }
}

extern "C" void kernel_launch(void* const* d_in, const int* in_sizes, int n_in,
                              void* d_out, int out_size, void* d_ws, size_t ws_size,
                              hipStream_t stream) {
    const float* x     = (const float*)d_in[0];
    const float* n1w   = (const float*)d_in[1];
    const float* n1b   = (const float*)d_in[2];
    const float* qkvw  = (const float*)d_in[3];
    const float* qkvb  = (const float*)d_in[4];
    const float* relb  = (const float*)d_in[5];
    const float* projw = (const float*)d_in[6];
    const float* projb = (const float*)d_in[7];
    const float* n2w   = (const float*)d_in[8];
    const float* n2b   = (const float*)d_in[9];
    const float* fc1w  = (const float*)d_in[10];
    const float* fc1b  = (const float*)d_in[11];
    const float* fc2w  = (const float*)d_in[12];
    const float* fc2b  = (const float*)d_in[13];
    float* out = (float*)d_out;

    swin_attn_kernel<<<BATCH * NW, 256, 0, stream>>>(
        x, n1w, n1b, qkvw, qkvb, relb, projw, projb, out);
    swin_mlp_kernel<<<(BATCH * HH * WWID) / 32, 256, 0, stream>>>(
        out, n2w, n2b, fc1w, fc1b, fc2w, fc2b);
}

// Round 2
// 416.573 us; speedup vs baseline: 22.8356x; 22.8356x over previous
//
#include <hip/hip_runtime.h>
#include <hip/hip_bf16.h>
#include <math.h>

#define BATCH 64
#define HH 56
#define CH 96
#define HEADS 3
#define HD 32
#define WIN 7
#define SHIFT 3
#define TOK 49
#define MLPH 384
#define SCALE 0.17677669529663687f  // 1/sqrt(32)

typedef short bf16x8 __attribute__((ext_vector_type(8)));
typedef float f32x4 __attribute__((ext_vector_type(4)));

#define MFMA(a, b, c) __builtin_amdgcn_mfma_f32_16x16x32_bf16((a), (b), (c), 0, 0, 0)

__device__ __forceinline__ bf16x8 ldfrag(const __hip_bfloat16* p) {
    return *(const bf16x8*)p;
}

// region label along one axis in rolled coords: [0,49)=0, [49,53)=1, [53,56)=2
__device__ __forceinline__ int region(int p) {
    return (p < HH - WIN) ? 0 : ((p < HH - SHIFT) ? 1 : 2);
}

// ws layout (bf16): [0) qkvw 288x96 | [27648) projw 96x96 | [36864) fc1w 384x96 | [73728) fc2w 96x384
__global__ __launch_bounds__(256) void convert_weights(
    const float* __restrict__ qkvw, const float* __restrict__ projw,
    const float* __restrict__ fc1w, const float* __restrict__ fc2w,
    __hip_bfloat16* __restrict__ ws)
{
    int i = blockIdx.x * 256 + threadIdx.x;
    if (i < 27648)       ws[i] = __float2bfloat16(qkvw[i]);
    else if (i < 36864)  ws[i] = __float2bfloat16(projw[i - 27648]);
    else if (i < 73728)  ws[i] = __float2bfloat16(fc1w[i - 36864]);
    else if (i < 110592) ws[i] = __float2bfloat16(fc2w[i - 73728]);
}

__global__ __launch_bounds__(256) void swin_attn(
    const float* __restrict__ x,
    const float* __restrict__ n1w, const float* __restrict__ n1b,
    const __hip_bfloat16* __restrict__ wqkv, const float* __restrict__ qkvb,
    const float* __restrict__ relb,
    const __hip_bfloat16* __restrict__ wproj, const float* __restrict__ projb,
    float* __restrict__ out)
{
    // XL doubles as AO (attention output) after qkv is consumed.
    __shared__ __align__(16) __hip_bfloat16 XL[64][104];
    __shared__ __align__(16) __hip_bfloat16 Qf[64][104];
    __shared__ __align__(16) __hip_bfloat16 Kf[64][104];
    __shared__ __align__(16) __hip_bfloat16 Vt[96][72];
    __shared__ __align__(16) float S[64][65];       // scores fp32; Pb (bf16 [64][72]) overlays it
    __shared__ float relbS[507];
    __shared__ int rowidx[TOK];
    __shared__ char r9[TOK], qdv[TOK], qmd[TOK];

    const int blk = blockIdx.x;
    const int b = blk >> 6;
    const int win = blk & 63;
    const int wi = win >> 3, wj = win & 7;
    const int tid = threadIdx.x;
    const int lane = tid & 63, w = tid >> 6;
    const size_t bbase = (size_t)b * (HH * HH * CH);

    // ---- init tables ----
    if (tid < TOK) {
        int ti = tid / WIN, tj = tid - WIN * (tid / WIN);
        qdv[tid] = (char)ti; qmd[tid] = (char)tj;
        int ph = (wi * WIN + ti + SHIFT) % HH;
        int pw = (wj * WIN + tj + SHIFT) % HH;
        rowidx[tid] = ph * HH + pw;
        r9[tid] = (char)(region(wi * WIN + ti) * 3 + region(wj * WIN + tj));
    }
    for (int i = tid; i < 507; i += 256) relbS[i] = relb[i];
    // zero pad rows of XL (rows 49..63, cols 0..95)
    for (int i = tid; i < 15 * CH; i += 256) {
        int r = 49 + i / CH, c = i - (i / CH) * CH;
        XL[r][c] = __float2bfloat16(0.f);
    }
    __syncthreads();

    // ---- LN1 (4 threads per row, shfl reduce) ----
    {
        int r = tid >> 2, p = tid & 3;
        float vals[24];
        float s = 0.f, s2 = 0.f;
        if (r < TOK) {
            const float* xr = x + bbase + (size_t)rowidx[r] * CH + p * 24;
            #pragma unroll
            for (int i = 0; i < 24; ++i) { vals[i] = xr[i]; s += vals[i]; s2 += vals[i] * vals[i]; }
        }
        s  += __shfl_xor(s, 1);  s  += __shfl_xor(s, 2);
        s2 += __shfl_xor(s2, 1); s2 += __shfl_xor(s2, 2);
        if (r < TOK) {
            float m = s * (1.f / CH);
            float rstd = rsqrtf(s2 * (1.f / CH) - m * m + 1e-5f);
            #pragma unroll
            for (int i = 0; i < 24; ++i) {
                int c = p * 24 + i;
                XL[r][c] = __float2bfloat16((vals[i] - m) * rstd * n1w[c] + n1b[c]);
            }
        }
    }
    __syncthreads();

    // ---- qkv GEMM: [64,96] @ [288,96]^T, wave w owns M-tile w ----
    {
        int arow = w * 16 + (lane & 15);
        int k0 = (lane >> 4) * 8;
        bf16x8 a0 = ldfrag(&XL[arow][k0]);
        bf16x8 a1 = ldfrag(&XL[arow][32 + k0]);
        bf16x8 a2 = ldfrag(&XL[arow][64 + k0]);
        for (int n = 0; n < 18; ++n) {
            int ncol = n * 16 + (lane & 15);
            const __hip_bfloat16* wb = wqkv + ncol * CH + k0;
            f32x4 acc = {0.f, 0.f, 0.f, 0.f};
            acc = MFMA(a0, ldfrag(wb), acc);
            acc = MFMA(a1, ldfrag(wb + 32), acc);
            acc = MFMA(a2, ldfrag(wb + 64), acc);
            float bias = qkvb[ncol];
            int rbase = w * 16 + ((lane >> 4) << 2);
            #pragma unroll
            for (int j = 0; j < 4; ++j) {
                float v = acc[j] + bias;
                int tok = rbase + j;
                if (ncol < 96)       Qf[tok][ncol] = __float2bfloat16(v * SCALE);
                else if (ncol < 192) Kf[tok][ncol - 96] = __float2bfloat16(v);
                else                 Vt[ncol - 192][tok] = __float2bfloat16(v);
            }
        }
    }
    __syncthreads();

    __hip_bfloat16* Pb = (__hip_bfloat16*)&S[0][0];   // [64][72] bf16 overlay

    for (int h = 0; h < HEADS; ++h) {
        // ---- scores: wave w = q-tile w, 4 k-tiles ----
        {
            int qrow = w * 16 + (lane & 15);
            int k0 = h * 32 + (lane >> 4) * 8;
            bf16x8 aq = ldfrag(&Qf[qrow][k0]);
            for (int kt = 0; kt < 4; ++kt) {
                bf16x8 bk = ldfrag(&Kf[kt * 16 + (lane & 15)][k0]);
                f32x4 s4 = {0.f, 0.f, 0.f, 0.f};
                s4 = MFMA(aq, bk, s4);
                int ktok = kt * 16 + (lane & 15);
                int qb = w * 16 + ((lane >> 4) << 2);
                #pragma unroll
                for (int j = 0; j < 4; ++j) {
                    int qtok = qb + j;
                    if (qtok < TOK && ktok < TOK) {
                        int dh = qdv[qtok] - qdv[ktok] + 6;
                        int dw = qmd[qtok] - qmd[ktok] + 6;
                        float v = s4[j] + relbS[(dh * 13 + dw) * HEADS + h];
                        if (r9[qtok] != r9[ktok]) v -= 100.f;
                        S[qtok][ktok] = v;
                    }
                }
            }
        }
        __syncthreads();

        // ---- softmax (4 threads/row) + bf16 convert into Pb (overlays S) ----
        {
            int r = tid >> 2, p = tid & 3;
            float e[16];
            #pragma unroll
            for (int i = 0; i < 16; ++i) e[i] = 0.f;
            float m = -1e30f, sum = 0.f;
            if (r < TOK) {
                #pragma unroll
                for (int i = 0; i < 16; ++i) {
                    int c = p * 16 + i;
                    if (c < TOK) m = fmaxf(m, S[r][c]);
                }
            }
            m = fmaxf(m, __shfl_xor(m, 1)); m = fmaxf(m, __shfl_xor(m, 2));
            if (r < TOK) {
                #pragma unroll
                for (int i = 0; i < 16; ++i) {
                    int c = p * 16 + i;
                    if (c < TOK) { e[i] = __expf(S[r][c] - m); sum += e[i]; }
                }
            }
            sum += __shfl_xor(sum, 1); sum += __shfl_xor(sum, 2);
            float inv = (r < TOK) ? (1.f / sum) : 0.f;
            __syncthreads();   // all S reads complete before Pb overwrites
            #pragma unroll
            for (int i = 0; i < 16; ++i)
                Pb[r * 72 + p * 16 + i] = __float2bfloat16(e[i] * inv);
        }
        __syncthreads();

        // ---- PV: wave w = q-tile w, 2 d-tiles, K=64 (2 steps) ----
        {
            int prow = w * 16 + (lane & 15);
            int k0 = (lane >> 4) * 8;
            bf16x8 p0 = ldfrag(&Pb[prow * 72 + k0]);
            bf16x8 p1 = ldfrag(&Pb[prow * 72 + 32 + k0]);
            #pragma unroll
            for (int dt = 0; dt < 2; ++dt) {
                int vrow = h * 32 + dt * 16 + (lane & 15);
                f32x4 o = {0.f, 0.f, 0.f, 0.f};
                o = MFMA(p0, ldfrag(&Vt[vrow][k0]), o);
                o = MFMA(p1, ldfrag(&Vt[vrow][32 + k0]), o);
                int qb = w * 16 + ((lane >> 4) << 2);
                #pragma unroll
                for (int j = 0; j < 4; ++j)
                    XL[qb + j][h * 32 + dt * 16 + (lane & 15)] = __float2bfloat16(o[j]);
            }
        }
        __syncthreads();
    }

    // ---- proj + residual + scatter: AO(=XL)[64,96] @ [96,96]^T ----
    {
        int arow = w * 16 + (lane & 15);
        int k0 = (lane >> 4) * 8;
        bf16x8 a0 = ldfrag(&XL[arow][k0]);
        bf16x8 a1 = ldfrag(&XL[arow][32 + k0]);
        bf16x8 a2 = ldfrag(&XL[arow][64 + k0]);
        for (int n = 0; n < 6; ++n) {
            int col = n * 16 + (lane & 15);
            const __hip_bfloat16* wb = wproj + col * CH + k0;
            f32x4 acc = {0.f, 0.f, 0.f, 0.f};
            acc = MFMA(a0, ldfrag(wb), acc);
            acc = MFMA(a1, ldfrag(wb + 32), acc);
            acc = MFMA(a2, ldfrag(wb + 64), acc);
            float bias = projb[col];
            int qb = w * 16 + ((lane >> 4) << 2);
            #pragma unroll
            for (int j = 0; j < 4; ++j) {
                int tok = qb + j;
                if (tok < TOK) {
                    size_t gi = bbase + (size_t)rowidx[tok] * CH + col;
                    out[gi] = x[gi] + acc[j] + bias;
                }
            }
        }
    }
}

__global__ __launch_bounds__(256) void swin_mlp(
    float* __restrict__ out,
    const float* __restrict__ n2w, const float* __restrict__ n2b,
    const __hip_bfloat16* __restrict__ w1, const float* __restrict__ b1,
    const __hip_bfloat16* __restrict__ w2, const float* __restrict__ b2)
{
    __shared__ __align__(16) __hip_bfloat16 XL2[64][104];
    __shared__ __align__(16) __hip_bfloat16 Hs[64][392];

    const int tid = threadIdx.x;
    const int lane = tid & 63, w = tid >> 6;
    const size_t base = (size_t)blockIdx.x * 64 * CH;

    // ---- LN2 (4 threads per row) ----
    {
        int r = tid >> 2, p = tid & 3;
        float vals[24];
        float s = 0.f, s2 = 0.f;
        const float* xr = out + base + r * CH + p * 24;
        #pragma unroll
        for (int i = 0; i < 24; ++i) { vals[i] = xr[i]; s += vals[i]; s2 += vals[i] * vals[i]; }
        s  += __shfl_xor(s, 1);  s  += __shfl_xor(s, 2);
        s2 += __shfl_xor(s2, 1); s2 += __shfl_xor(s2, 2);
        float m = s * (1.f / CH);
        float rstd = rsqrtf(s2 * (1.f / CH) - m * m + 1e-5f);
        #pragma unroll
        for (int i = 0; i < 24; ++i) {
            int c = p * 24 + i;
            XL2[r][c] = __float2bfloat16((vals[i] - m) * rstd * n2w[c] + n2b[c]);
        }
    }
    __syncthreads();

    // ---- fc1 + exact GELU: [64,96] @ [384,96]^T ----
    {
        int arow = w * 16 + (lane & 15);
        int k0 = (lane >> 4) * 8;
        bf16x8 a0 = ldfrag(&XL2[arow][k0]);
        bf16x8 a1 = ldfrag(&XL2[arow][32 + k0]);
        bf16x8 a2 = ldfrag(&XL2[arow][64 + k0]);
        for (int n = 0; n < 24; ++n) {
            int col = n * 16 + (lane & 15);
            const __hip_bfloat16* wb = w1 + col * CH + k0;
            f32x4 acc = {0.f, 0.f, 0.f, 0.f};
            acc = MFMA(a0, ldfrag(wb), acc);
            acc = MFMA(a1, ldfrag(wb + 32), acc);
            acc = MFMA(a2, ldfrag(wb + 64), acc);
            float bias = b1[col];
            int rb = w * 16 + ((lane >> 4) << 2);
            #pragma unroll
            for (int j = 0; j < 4; ++j) {
                float v = acc[j] + bias;
                v = 0.5f * v * (1.f + erff(v * 0.70710678118654752f));
                Hs[rb + j][col] = __float2bfloat16(v);
            }
        }
    }
    __syncthreads();

    // ---- fc2 + residual: [64,384] @ [96,384]^T, 6 acc tiles/wave ----
    {
        int arow = w * 16 + (lane & 15);
        int k0 = (lane >> 4) * 8;
        f32x4 acc[6];
        #pragma unroll
        for (int n = 0; n < 6; ++n) acc[n] = (f32x4){0.f, 0.f, 0.f, 0.f};
        for (int k = 0; k < 12; ++k) {
            bf16x8 a = ldfrag(&Hs[arow][k * 32 + k0]);
            #pragma unroll
            for (int n = 0; n < 6; ++n) {
                const __hip_bfloat16* wb = w2 + (n * 16 + (lane & 15)) * MLPH + k * 32 + k0;
                acc[n] = MFMA(a, ldfrag(wb), acc[n]);
            }
        }
        #pragma unroll
        for (int n = 0; n < 6; ++n) {
            int col = n * 16 + (lane & 15);
            float bias = b2[col];
            int rb = w * 16 + ((lane >> 4) << 2);
            #pragma unroll
            for (int j = 0; j < 4; ++j) {
                size_t gi = base + (size_t)(rb + j) * CH + col;
                out[gi] = out[gi] + acc[n][j] + bias;
            }
        }
    }
}

extern "C" void kernel_launch(void* const* d_in, const int* in_sizes, int n_in,
                              void* d_out, int out_size, void* d_ws, size_t ws_size,
                              hipStream_t stream) {
    const float* x     = (const float*)d_in[0];
    const float* n1w   = (const float*)d_in[1];
    const float* n1b   = (const float*)d_in[2];
    const float* qkvw  = (const float*)d_in[3];
    const float* qkvb  = (const float*)d_in[4];
    const float* relb  = (const float*)d_in[5];
    const float* projw = (const float*)d_in[6];
    const float* projb = (const float*)d_in[7];
    const float* n2w   = (const float*)d_in[8];
    const float* n2b   = (const float*)d_in[9];
    const float* fc1w  = (const float*)d_in[10];
    const float* fc1b  = (const float*)d_in[11];
    const float* fc2w  = (const float*)d_in[12];
    const float* fc2b  = (const float*)d_in[13];
    float* out = (float*)d_out;

    __hip_bfloat16* wbf = (__hip_bfloat16*)d_ws;
    const __hip_bfloat16* wqkv  = wbf;
    const __hip_bfloat16* wproj = wbf + 27648;
    const __hip_bfloat16* wfc1  = wbf + 36864;
    const __hip_bfloat16* wfc2  = wbf + 73728;

    convert_weights<<<432, 256, 0, stream>>>(qkvw, projw, fc1w, fc2w, wbf);
    swin_attn<<<BATCH * 64, 256, 0, stream>>>(
        x, n1w, n1b, wqkv, qkvb, relb, wproj, projb, out);
    swin_mlp<<<(BATCH * HH * HH) / 64, 256, 0, stream>>>(
        out, n2w, n2b, wfc1, fc1b, wfc2, fc2b);
}

// Round 3
// 234.637 us; speedup vs baseline: 40.5421x; 1.7754x over previous
//
#include <hip/hip_runtime.h>
#include <hip/hip_bf16.h>
#include <math.h>

#define BATCH 64
#define HH 56
#define CH 96
#define HEADS 3
#define WIN 7
#define SHIFT 3
#define TOK 49
#define MLPH 384
#define SCALE 0.17677669529663687f  // 1/sqrt(32)

typedef short bf16x8 __attribute__((ext_vector_type(8)));
typedef float f32x4 __attribute__((ext_vector_type(4)));

#define MFMA(a, b, c) __builtin_amdgcn_mfma_f32_16x16x32_bf16((a), (b), (c), 0, 0, 0)

__device__ __forceinline__ bf16x8 ldfrag(const __hip_bfloat16* p) {
    return *(const bf16x8*)p;
}
__device__ __forceinline__ unsigned short f2bf(float f) {
    __hip_bfloat16 h = __float2bfloat16(f);
    unsigned short u; __builtin_memcpy(&u, &h, 2); return u;
}

// ws layout: bf16 weights [0,110592): qkvw 288x96 | projw 96x96 @27648 | fc1w 384x96 @36864 | fc2w 96x384 @73728
// then float btab[4 cat][3 h][64 k][64 q] at byte offset 221184 (196608 B)
__global__ __launch_bounds__(256) void prep(
    const float* __restrict__ qkvw, const float* __restrict__ projw,
    const float* __restrict__ fc1w, const float* __restrict__ fc2w,
    const float* __restrict__ relb,
    __hip_bfloat16* __restrict__ wbf, float* __restrict__ btab)
{
    int i = blockIdx.x * 256 + threadIdx.x;
    if (i < 27648)        wbf[i] = __float2bfloat16(qkvw[i]);
    else if (i < 36864)   wbf[i] = __float2bfloat16(projw[i - 27648]);
    else if (i < 73728)   wbf[i] = __float2bfloat16(fc1w[i - 36864]);
    else if (i < 110592)  wbf[i] = __float2bfloat16(fc2w[i - 73728]);
    else {
        int j = i - 110592;                 // [0, 49152)
        int cat = j / 12288;
        int r = j - cat * 12288;
        int h = r >> 12;
        int r2 = r & 4095;
        int k = r2 >> 6, q = r2 & 63;
        float v;
        if (k >= TOK) v = -10000.f;         // kill pad-k columns in softmax
        else if (q >= TOK) v = 0.f;         // pad-q rows: don't care
        else {
            int qi = q / WIN, qj = q - qi * WIN;
            int ki = k / WIN, kj = k - ki * WIN;
            int ridx = (qi - ki + 6) * 13 + (qj - kj + 6);
            v = relb[ridx * HEADS + h];
            int rqh = (cat & 2) ? (qi < 4 ? 1 : 2) : 0;
            int rqw = (cat & 1) ? (qj < 4 ? 1 : 2) : 0;
            int rkh = (cat & 2) ? (ki < 4 ? 1 : 2) : 0;
            int rkw = (cat & 1) ? (kj < 4 ? 1 : 2) : 0;
            if (rqh * 3 + rqw != rkh * 3 + rkw) v -= 100.f;
        }
        btab[j] = v;
    }
}

__global__ __launch_bounds__(256) void swin_attn(
    const float* __restrict__ x,
    const float* __restrict__ n1w, const float* __restrict__ n1b,
    const __hip_bfloat16* __restrict__ wqkv, const float* __restrict__ qkvb,
    const float* __restrict__ btab,
    const __hip_bfloat16* __restrict__ wproj, const float* __restrict__ projb,
    float* __restrict__ out)
{
    // XL holds LN'd input for qkv, then is overwritten with attention output for proj.
    __shared__ __align__(16) __hip_bfloat16 XL[64][104];
    __shared__ __align__(16) __hip_bfloat16 Qf[64][104];
    __shared__ __align__(16) __hip_bfloat16 Kf[64][104];
    __shared__ __align__(16) __hip_bfloat16 Vt[96][72];   // V transposed: [d][tok]
    __shared__ __align__(16) __hip_bfloat16 Pw[4][16][72]; // per-wave P staging

    const int blk = blockIdx.x;
    const int b = blk >> 6, win = blk & 63;
    const int wi = win >> 3, wj = win & 7;
    const int cat = ((wi == 7) << 1) | (wj == 7);
    const int tid = threadIdx.x;
    const int lane = tid & 63, w = tid >> 6;
    const int lr = lane & 15, g = lane >> 4;
    const int k0 = g * 8;
    const size_t bbase = (size_t)b * (HH * HH * CH);

    // ---- LN1 + shifted-window gather (4 threads/row); zero pad rows ----
    {
        int r = tid >> 2, p = tid & 3;
        if (r < TOK) {
            int ti = r / WIN, tj = r - (r / WIN) * WIN;
            int ph = wi * WIN + ti + SHIFT; if (ph >= HH) ph -= HH;
            int pw = wj * WIN + tj + SHIFT; if (pw >= HH) pw -= HH;
            const float4* xr = (const float4*)(x + bbase + (size_t)(ph * HH + pw) * CH + p * 24);
            float v[24]; float s = 0.f, s2 = 0.f;
            #pragma unroll
            for (int i = 0; i < 6; ++i) {
                float4 f = xr[i];
                v[4*i] = f.x; v[4*i+1] = f.y; v[4*i+2] = f.z; v[4*i+3] = f.w;
            }
            #pragma unroll
            for (int i = 0; i < 24; ++i) { s += v[i]; s2 += v[i] * v[i]; }
            s  += __shfl_xor(s, 1);  s  += __shfl_xor(s, 2);
            s2 += __shfl_xor(s2, 1); s2 += __shfl_xor(s2, 2);
            float mu = s * (1.f / CH);
            float rstd = rsqrtf(s2 * (1.f / CH) - mu * mu + 1e-5f);
            #pragma unroll
            for (int i = 0; i < 24; ++i) {
                int c = p * 24 + i;
                XL[r][c] = __float2bfloat16((v[i] - mu) * rstd * n1w[c] + n1b[c]);
            }
        } else {
            #pragma unroll
            for (int i = 0; i < 24; ++i) XL[r][p * 24 + i] = __float2bfloat16(0.f);
        }
    }
    __syncthreads();

    // ---- qkv GEMM: wave owns N-slice, B-fragment reused across 4 M-tiles ----
    {
        bf16x8 A[4][3];
        #pragma unroll
        for (int mt = 0; mt < 4; ++mt)
            #pragma unroll
            for (int ks = 0; ks < 3; ++ks)
                A[mt][ks] = ldfrag(&XL[mt * 16 + lr][ks * 32 + k0]);
        for (int n = w; n < 18; n += 4) {
            int ncol = n * 16 + lr;
            const __hip_bfloat16* wb = wqkv + ncol * CH + k0;
            f32x4 acc[4];
            #pragma unroll
            for (int mt = 0; mt < 4; ++mt) acc[mt] = (f32x4){0.f, 0.f, 0.f, 0.f};
            #pragma unroll
            for (int ks = 0; ks < 3; ++ks) {
                bf16x8 bf = ldfrag(wb + ks * 32);
                #pragma unroll
                for (int mt = 0; mt < 4; ++mt) acc[mt] = MFMA(A[mt][ks], bf, acc[mt]);
            }
            float bias = qkvb[ncol];
            #pragma unroll
            for (int mt = 0; mt < 4; ++mt)
                #pragma unroll
                for (int j = 0; j < 4; ++j) {
                    int tok = mt * 16 + g * 4 + j;
                    float v = acc[mt][j] + bias;
                    if (n < 6)       Qf[tok][ncol] = __float2bfloat16(v * SCALE);
                    else if (n < 12) Kf[tok][ncol - 96] = __float2bfloat16(v);
                    else             Vt[ncol - 192][tok] = __float2bfloat16(v);
                }
        }
    }
    __syncthreads();

    // ---- attention units: (h, qt), wave w handles qt=w for all 3 heads; no barriers inside ----
    for (int u = w; u < 12; u += 4) {
        int h = u >> 2, qt = u & 3;
        // swapped QK^T: D[k][q], lane holds q = qt*16+lr, k = kt*16 + 4g + reg
        bf16x8 qfrag = ldfrag(&Qf[qt * 16 + lr][h * 32 + k0]);
        f32x4 s[4];
        #pragma unroll
        for (int kt = 0; kt < 4; ++kt) {
            f32x4 z = {0.f, 0.f, 0.f, 0.f};
            s[kt] = MFMA(ldfrag(&Kf[kt * 16 + lr][h * 32 + k0]), qfrag, z);
        }
        const float* bt = btab + ((cat * HEADS + h) << 12) + qt * 16 + lr;
        #pragma unroll
        for (int kt = 0; kt < 4; ++kt)
            #pragma unroll
            for (int j = 0; j < 4; ++j)
                s[kt][j] += bt[(kt * 16 + g * 4 + j) << 6];
        // in-register softmax over k (row q spread across lane groups: xor 16, 32)
        float m = -1e30f;
        #pragma unroll
        for (int kt = 0; kt < 4; ++kt)
            #pragma unroll
            for (int j = 0; j < 4; ++j) m = fmaxf(m, s[kt][j]);
        m = fmaxf(m, __shfl_xor(m, 16));
        m = fmaxf(m, __shfl_xor(m, 32));
        float e[4][4]; float sum = 0.f;
        #pragma unroll
        for (int kt = 0; kt < 4; ++kt)
            #pragma unroll
            for (int j = 0; j < 4; ++j) { e[kt][j] = __expf(s[kt][j] - m); sum += e[kt][j]; }
        sum += __shfl_xor(sum, 16);
        sum += __shfl_xor(sum, 32);
        float inv = 1.f / sum;
        #pragma unroll
        for (int kt = 0; kt < 4; ++kt) {
            ushort2 p0, p1;
            p0.x = f2bf(e[kt][0] * inv); p0.y = f2bf(e[kt][1] * inv);
            p1.x = f2bf(e[kt][2] * inv); p1.y = f2bf(e[kt][3] * inv);
            *(ushort2*)&Pw[w][lr][kt * 16 + g * 4]     = p0;
            *(ushort2*)&Pw[w][lr][kt * 16 + g * 4 + 2] = p1;
        }
        // PV: out[q][d] = sum_k P[q][k] V^T[d][k]
        #pragma unroll
        for (int dt = 0; dt < 2; ++dt) {
            f32x4 o = {0.f, 0.f, 0.f, 0.f};
            #pragma unroll
            for (int ks = 0; ks < 2; ++ks) {
                bf16x8 pa = ldfrag(&Pw[w][lr][ks * 32 + k0]);
                bf16x8 vb = ldfrag(&Vt[h * 32 + dt * 16 + lr][ks * 32 + k0]);
                o = MFMA(pa, vb, o);
            }
            #pragma unroll
            for (int j = 0; j < 4; ++j)
                XL[qt * 16 + g * 4 + j][h * 32 + dt * 16 + lr] = __float2bfloat16(o[j]);
        }
    }
    __syncthreads();

    // ---- proj + residual + inverse-shift scatter ----
    {
        bf16x8 A[4][3];
        #pragma unroll
        for (int mt = 0; mt < 4; ++mt)
            #pragma unroll
            for (int ks = 0; ks < 3; ++ks)
                A[mt][ks] = ldfrag(&XL[mt * 16 + lr][ks * 32 + k0]);
        for (int n = w; n < 6; n += 4) {
            int ncol = n * 16 + lr;
            const __hip_bfloat16* wb = wproj + ncol * CH + k0;
            f32x4 acc[4];
            #pragma unroll
            for (int mt = 0; mt < 4; ++mt) acc[mt] = (f32x4){0.f, 0.f, 0.f, 0.f};
            #pragma unroll
            for (int ks = 0; ks < 3; ++ks) {
                bf16x8 bf = ldfrag(wb + ks * 32);
                #pragma unroll
                for (int mt = 0; mt < 4; ++mt) acc[mt] = MFMA(A[mt][ks], bf, acc[mt]);
            }
            float bias = projb[ncol];
            #pragma unroll
            for (int mt = 0; mt < 4; ++mt)
                #pragma unroll
                for (int j = 0; j < 4; ++j) {
                    int tok = mt * 16 + g * 4 + j;
                    if (tok < TOK) {
                        int ti = tok / WIN, tj = tok - (tok / WIN) * WIN;
                        int ph = wi * WIN + ti + SHIFT; if (ph >= HH) ph -= HH;
                        int pw = wj * WIN + tj + SHIFT; if (pw >= HH) pw -= HH;
                        size_t gi = bbase + (size_t)(ph * HH + pw) * CH + ncol;
                        out[gi] = x[gi] + acc[mt][j] + bias;
                    }
                }
        }
    }
}

__global__ __launch_bounds__(256) void swin_mlp(
    float* __restrict__ out,
    const float* __restrict__ n2w, const float* __restrict__ n2b,
    const __hip_bfloat16* __restrict__ w1, const float* __restrict__ b1,
    const __hip_bfloat16* __restrict__ w2, const float* __restrict__ b2)
{
    __shared__ __align__(16) __hip_bfloat16 XL2[64][104];
    __shared__ __align__(16) __hip_bfloat16 Hs[64][392];

    const int tid = threadIdx.x;
    const int lane = tid & 63, w = tid >> 6;
    const int lr = lane & 15, g = lane >> 4, k0 = g * 8;
    const size_t base = (size_t)blockIdx.x * 64 * CH;

    // ---- LN2 ----
    {
        int r = tid >> 2, p = tid & 3;
        const float4* xr = (const float4*)(out + base + (size_t)r * CH + p * 24);
        float v[24]; float s = 0.f, s2 = 0.f;
        #pragma unroll
        for (int i = 0; i < 6; ++i) {
            float4 f = xr[i];
            v[4*i] = f.x; v[4*i+1] = f.y; v[4*i+2] = f.z; v[4*i+3] = f.w;
        }
        #pragma unroll
        for (int i = 0; i < 24; ++i) { s += v[i]; s2 += v[i] * v[i]; }
        s  += __shfl_xor(s, 1);  s  += __shfl_xor(s, 2);
        s2 += __shfl_xor(s2, 1); s2 += __shfl_xor(s2, 2);
        float mu = s * (1.f / CH);
        float rstd = rsqrtf(s2 * (1.f / CH) - mu * mu + 1e-5f);
        #pragma unroll
        for (int i = 0; i < 24; ++i) {
            int c = p * 24 + i;
            XL2[r][c] = __float2bfloat16((v[i] - mu) * rstd * n2w[c] + n2b[c]);
        }
    }
    __syncthreads();

    // ---- fc1 + sigmoid-GELU: wave owns 6 of 24 N-tiles, B reused across 4 M-tiles ----
    {
        bf16x8 A[4][3];
        #pragma unroll
        for (int mt = 0; mt < 4; ++mt)
            #pragma unroll
            for (int ks = 0; ks < 3; ++ks)
                A[mt][ks] = ldfrag(&XL2[mt * 16 + lr][ks * 32 + k0]);
        for (int n = w; n < 24; n += 4) {
            int ncol = n * 16 + lr;
            const __hip_bfloat16* wb = w1 + ncol * CH + k0;
            f32x4 acc[4];
            #pragma unroll
            for (int mt = 0; mt < 4; ++mt) acc[mt] = (f32x4){0.f, 0.f, 0.f, 0.f};
            #pragma unroll
            for (int ks = 0; ks < 3; ++ks) {
                bf16x8 bf = ldfrag(wb + ks * 32);
                #pragma unroll
                for (int mt = 0; mt < 4; ++mt) acc[mt] = MFMA(A[mt][ks], bf, acc[mt]);
            }
            float bias = b1[ncol];
            #pragma unroll
            for (int mt = 0; mt < 4; ++mt)
                #pragma unroll
                for (int j = 0; j < 4; ++j) {
                    float v = acc[mt][j] + bias;
                    float ge = v / (1.f + __expf(-1.702f * v));
                    Hs[mt * 16 + g * 4 + j][ncol] = __float2bfloat16(ge);
                }
        }
    }
    __syncthreads();

    // ---- fc2 + residual: 2x2 (M-half x N-half) wave split, B reused across 2 M-tiles ----
    {
        int mh = w & 1, nh = w >> 1;
        f32x4 acc[3][2];
        #pragma unroll
        for (int nt = 0; nt < 3; ++nt)
            #pragma unroll
            for (int mi = 0; mi < 2; ++mi) acc[nt][mi] = (f32x4){0.f, 0.f, 0.f, 0.f};
        for (int k = 0; k < 12; ++k) {
            bf16x8 a0 = ldfrag(&Hs[mh * 32 + lr][k * 32 + k0]);
            bf16x8 a1 = ldfrag(&Hs[mh * 32 + 16 + lr][k * 32 + k0]);
            #pragma unroll
            for (int nt = 0; nt < 3; ++nt) {
                bf16x8 bf = ldfrag(w2 + (nh * 48 + nt * 16 + lr) * MLPH + k * 32 + k0);
                acc[nt][0] = MFMA(a0, bf, acc[nt][0]);
                acc[nt][1] = MFMA(a1, bf, acc[nt][1]);
            }
        }
        #pragma unroll
        for (int nt = 0; nt < 3; ++nt) {
            int col = nh * 48 + nt * 16 + lr;
            float bias = b2[col];
            #pragma unroll
            for (int mi = 0; mi < 2; ++mi)
                #pragma unroll
                for (int j = 0; j < 4; ++j) {
                    int tok = mh * 32 + mi * 16 + g * 4 + j;
                    size_t gi = base + (size_t)tok * CH + col;
                    out[gi] += acc[nt][mi][j] + bias;
                }
        }
    }
}

extern "C" void kernel_launch(void* const* d_in, const int* in_sizes, int n_in,
                              void* d_out, int out_size, void* d_ws, size_t ws_size,
                              hipStream_t stream) {
    const float* x     = (const float*)d_in[0];
    const float* n1w   = (const float*)d_in[1];
    const float* n1b   = (const float*)d_in[2];
    const float* qkvw  = (const float*)d_in[3];
    const float* qkvb  = (const float*)d_in[4];
    const float* relb  = (const float*)d_in[5];
    const float* projw = (const float*)d_in[6];
    const float* projb = (const float*)d_in[7];
    const float* n2w   = (const float*)d_in[8];
    const float* n2b   = (const float*)d_in[9];
    const float* fc1w  = (const float*)d_in[10];
    const float* fc1b  = (const float*)d_in[11];
    const float* fc2w  = (const float*)d_in[12];
    const float* fc2b  = (const float*)d_in[13];
    float* out = (float*)d_out;

    __hip_bfloat16* wbf = (__hip_bfloat16*)d_ws;
    float* btab = (float*)((char*)d_ws + 221184);
    const __hip_bfloat16* wqkv  = wbf;
    const __hip_bfloat16* wproj = wbf + 27648;
    const __hip_bfloat16* wfc1  = wbf + 36864;
    const __hip_bfloat16* wfc2  = wbf + 73728;

    prep<<<624, 256, 0, stream>>>(qkvw, projw, fc1w, fc2w, relb, wbf, btab);
    swin_attn<<<BATCH * 64, 256, 0, stream>>>(
        x, n1w, n1b, wqkv, qkvb, btab, wproj, projb, out);
    swin_mlp<<<(BATCH * HH * HH) / 64, 256, 0, stream>>>(
        out, n2w, n2b, wfc1, fc1b, wfc2, fc2b);
}

// Round 7
// 202.508 us; speedup vs baseline: 46.9744x; 1.1587x over previous
//
#include <hip/hip_runtime.h>
#include <hip/hip_bf16.h>
#include <math.h>

#define BATCH 64
#define HH 56
#define CH 96
#define HEADS 3
#define WIN 7
#define SHIFT 3
#define TOK 49
#define MLPH 384
#define SCALE 0.17677669529663687f  // 1/sqrt(32)

typedef short bf16x8 __attribute__((ext_vector_type(8)));
typedef float f32x4 __attribute__((ext_vector_type(4)));

#define MFMA(a, b, c) __builtin_amdgcn_mfma_f32_16x16x32_bf16((a), (b), (c), 0, 0, 0)
#define MEMFENCE() asm volatile("" ::: "memory")

__device__ __forceinline__ bf16x8 ldfrag(const __hip_bfloat16* p) {
    return *(const bf16x8*)p;
}
__device__ __forceinline__ unsigned short f2bf(float f) {
    __hip_bfloat16 h = __float2bfloat16(f);
    unsigned short u; __builtin_memcpy(&u, &h, 2); return u;
}

// ws layout: bf16 weights [0,110592): qkvw 288x96 | projw 96x96 @27648 | fc1w 384x96 @36864 | fc2w 96x384 @73728
// then float btab[4 cat][3 h][64 q][64 k] at byte offset 221184 (196608 B)
__global__ __launch_bounds__(256) void prep(
    const float* __restrict__ qkvw, const float* __restrict__ projw,
    const float* __restrict__ fc1w, const float* __restrict__ fc2w,
    const float* __restrict__ relb,
    __hip_bfloat16* __restrict__ wbf, float* __restrict__ btab)
{
    int i = blockIdx.x * 256 + threadIdx.x;
    if (i < 27648)        wbf[i] = __float2bfloat16(qkvw[i]);
    else if (i < 36864)   wbf[i] = __float2bfloat16(projw[i - 27648]);
    else if (i < 73728)   wbf[i] = __float2bfloat16(fc1w[i - 36864]);
    else if (i < 110592)  wbf[i] = __float2bfloat16(fc2w[i - 73728]);
    else {
        int j = i - 110592;                 // [0, 49152)
        int cat = j / 12288;
        int r = j - cat * 12288;
        int h = r >> 12;
        int r2 = r & 4095;
        int q = r2 >> 6, k = r2 & 63;       // q outer, k inner (float4 along k)
        float v;
        if (k >= TOK) v = -10000.f;         // kill pad-k columns in softmax
        else if (q >= TOK) v = 0.f;         // pad-q rows: don't care
        else {
            int qi = q / WIN, qj = q - qi * WIN;
            int ki = k / WIN, kj = k - ki * WIN;
            int ridx = (qi - ki + 6) * 13 + (qj - kj + 6);
            v = relb[ridx * HEADS + h];
            int rqh = (cat & 2) ? (qi < 4 ? 1 : 2) : 0;
            int rqw = (cat & 1) ? (qj < 4 ? 1 : 2) : 0;
            int rkh = (cat & 2) ? (ki < 4 ? 1 : 2) : 0;
            int rkw = (cat & 1) ? (kj < 4 ? 1 : 2) : 0;
            if (rqh * 3 + rqw != rkh * 3 + rkw) v -= 100.f;
        }
        btab[j] = v;
    }
}

__global__ __launch_bounds__(256) void swin_attn(
    const float* __restrict__ x,
    const float* __restrict__ n1w, const float* __restrict__ n1b,
    const __hip_bfloat16* __restrict__ wqkv, const float* __restrict__ qkvb,
    const float* __restrict__ btab,
    const __hip_bfloat16* __restrict__ wproj, const float* __restrict__ projb,
    float* __restrict__ out)
{
    // XL holds LN'd input for qkv, then is overwritten with attention output for proj.
    __shared__ __align__(16) __hip_bfloat16 XL[64][104];
    __shared__ __align__(16) __hip_bfloat16 Qf[64][104];
    __shared__ __align__(16) __hip_bfloat16 Kf[64][104];
    __shared__ __align__(16) __hip_bfloat16 Vt[96][72];    // V transposed: [d][tok]
    __shared__ __align__(16) __hip_bfloat16 Pw[4][16][72]; // per-wave P staging

    const int blk = blockIdx.x;
    const int b = blk >> 6, win = blk & 63;
    const int wi = win >> 3, wj = win & 7;
    const int cat = ((wi == 7) << 1) | (wj == 7);
    const int tid = threadIdx.x;
    const int lane = tid & 63, w = tid >> 6;
    const int lr = lane & 15, g = lane >> 4;
    const int k0 = g * 8;
    const size_t bbase = (size_t)b * (HH * HH * CH);

    // ---- LN1 + shifted-window gather (4 threads/row); zero pad rows ----
    {
        int r = tid >> 2, p = tid & 3;
        if (r < TOK) {
            int ti = r / WIN, tj = r - (r / WIN) * WIN;
            int ph = wi * WIN + ti + SHIFT; if (ph >= HH) ph -= HH;
            int pw = wj * WIN + tj + SHIFT; if (pw >= HH) pw -= HH;
            const float4* xr = (const float4*)(x + bbase + (size_t)(ph * HH + pw) * CH + p * 24);
            float v[24]; float s = 0.f, s2 = 0.f;
            #pragma unroll
            for (int i = 0; i < 6; ++i) {
                float4 f = xr[i];
                v[4*i] = f.x; v[4*i+1] = f.y; v[4*i+2] = f.z; v[4*i+3] = f.w;
            }
            #pragma unroll
            for (int i = 0; i < 24; ++i) { s += v[i]; s2 += v[i] * v[i]; }
            s  += __shfl_xor(s, 1);  s  += __shfl_xor(s, 2);
            s2 += __shfl_xor(s2, 1); s2 += __shfl_xor(s2, 2);
            float mu = s * (1.f / CH);
            float rstd = rsqrtf(s2 * (1.f / CH) - mu * mu + 1e-5f);
            #pragma unroll
            for (int i = 0; i < 24; ++i) {
                int c = p * 24 + i;
                XL[r][c] = __float2bfloat16((v[i] - mu) * rstd * n1w[c] + n1b[c]);
            }
        } else {
            #pragma unroll
            for (int i = 0; i < 24; ++i) XL[r][p * 24 + i] = __float2bfloat16(0.f);
        }
    }
    __syncthreads();

    // ---- qkv GEMM: wave owns N-slice, B-fragment reused across 4 M-tiles ----
    {
        bf16x8 A[4][3];
        #pragma unroll
        for (int mt = 0; mt < 4; ++mt)
            #pragma unroll
            for (int ks = 0; ks < 3; ++ks)
                A[mt][ks] = ldfrag(&XL[mt * 16 + lr][ks * 32 + k0]);
        #pragma unroll
        for (int nn = 0; nn < 5; ++nn) {
            int n = w + 4 * nn;
            if (n < 18) {
                int ncol = n * 16 + lr;
                const __hip_bfloat16* wb = wqkv + ncol * CH + k0;
                f32x4 acc[4];
                #pragma unroll
                for (int mt = 0; mt < 4; ++mt) acc[mt] = (f32x4){0.f, 0.f, 0.f, 0.f};
                #pragma unroll
                for (int ks = 0; ks < 3; ++ks) {
                    bf16x8 bf = ldfrag(wb + ks * 32);
                    #pragma unroll
                    for (int mt = 0; mt < 4; ++mt) acc[mt] = MFMA(A[mt][ks], bf, acc[mt]);
                }
                float bias = qkvb[ncol];
                #pragma unroll
                for (int mt = 0; mt < 4; ++mt)
                    #pragma unroll
                    for (int j = 0; j < 4; ++j) {
                        int tok = mt * 16 + g * 4 + j;
                        float v = acc[mt][j] + bias;
                        if (n < 6)       Qf[tok][ncol] = __float2bfloat16(v * SCALE);
                        else if (n < 12) Kf[tok][ncol - 96] = __float2bfloat16(v);
                        else             Vt[ncol - 192][tok] = __float2bfloat16(v);
                    }
            }
        }
    }
    __syncthreads();

    // ---- attention units: wave w handles qt=w for all 3 heads; no barriers inside ----
    for (int u = w; u < 12; u += 4) {
        int h = u >> 2, qt = u & 3;
        // swapped QK^T: D[k][q], lane holds q = qt*16+lr, k = kt*16 + 4g + j
        bf16x8 qfrag = ldfrag(&Qf[qt * 16 + lr][h * 32 + k0]);
        f32x4 s[4];
        #pragma unroll
        for (int kt = 0; kt < 4; ++kt) {
            f32x4 z = {0.f, 0.f, 0.f, 0.f};
            s[kt] = MFMA(ldfrag(&Kf[kt * 16 + lr][h * 32 + k0]), qfrag, z);
        }
        const float* bt = btab + (((cat * HEADS + h) << 12) | ((qt * 16 + lr) << 6));
        #pragma unroll
        for (int kt = 0; kt < 4; ++kt)
            s[kt] += *(const f32x4*)(bt + kt * 16 + 4 * g);
        // in-register softmax over k (q = lr fixed; k spread across g: xor 16,32)
        float m = -1e30f;
        #pragma unroll
        for (int kt = 0; kt < 4; ++kt)
            #pragma unroll
            for (int j = 0; j < 4; ++j) m = fmaxf(m, s[kt][j]);
        m = fmaxf(m, __shfl_xor(m, 16));
        m = fmaxf(m, __shfl_xor(m, 32));
        float e[4][4]; float sum = 0.f;
        #pragma unroll
        for (int kt = 0; kt < 4; ++kt)
            #pragma unroll
            for (int j = 0; j < 4; ++j) { e[kt][j] = __expf(s[kt][j] - m); sum += e[kt][j]; }
        sum += __shfl_xor(sum, 16);
        sum += __shfl_xor(sum, 32);
        float inv = 1.f / sum;
        #pragma unroll
        for (int kt = 0; kt < 4; ++kt) {
            ushort2 p0, p1;
            p0.x = f2bf(e[kt][0] * inv); p0.y = f2bf(e[kt][1] * inv);
            p1.x = f2bf(e[kt][2] * inv); p1.y = f2bf(e[kt][3] * inv);
            *(ushort2*)&Pw[w][lr][kt * 16 + g * 4]     = p0;
            *(ushort2*)&Pw[w][lr][kt * 16 + g * 4 + 2] = p1;
        }
        MEMFENCE();   // Pw stores -> PV fragment loads (same-wave rows; r3-proven pattern)
        // PV: out[q][d] = sum_k P[q][k] V^T[d][k]
        #pragma unroll
        for (int dt = 0; dt < 2; ++dt) {
            f32x4 o = {0.f, 0.f, 0.f, 0.f};
            #pragma unroll
            for (int ks = 0; ks < 2; ++ks) {
                bf16x8 pa = ldfrag(&Pw[w][lr][ks * 32 + k0]);
                bf16x8 vb = ldfrag(&Vt[h * 32 + dt * 16 + lr][ks * 32 + k0]);
                o = MFMA(pa, vb, o);
            }
            #pragma unroll
            for (int j = 0; j < 4; ++j)
                XL[qt * 16 + g * 4 + j][h * 32 + dt * 16 + lr] = __float2bfloat16(o[j]);
        }
    }
    __syncthreads();

    // ---- proj + residual + inverse-shift scatter ----
    {
        bf16x8 A[4][3];
        #pragma unroll
        for (int mt = 0; mt < 4; ++mt)
            #pragma unroll
            for (int ks = 0; ks < 3; ++ks)
                A[mt][ks] = ldfrag(&XL[mt * 16 + lr][ks * 32 + k0]);
        #pragma unroll
        for (int nn = 0; nn < 2; ++nn) {
            int n = w + 4 * nn;
            if (n < 6) {
                int ncol = n * 16 + lr;
                const __hip_bfloat16* wb = wproj + ncol * CH + k0;
                f32x4 acc[4];
                #pragma unroll
                for (int mt = 0; mt < 4; ++mt) acc[mt] = (f32x4){0.f, 0.f, 0.f, 0.f};
                #pragma unroll
                for (int ks = 0; ks < 3; ++ks) {
                    bf16x8 bf = ldfrag(wb + ks * 32);
                    #pragma unroll
                    for (int mt = 0; mt < 4; ++mt) acc[mt] = MFMA(A[mt][ks], bf, acc[mt]);
                }
                float bias = projb[ncol];
                #pragma unroll
                for (int mt = 0; mt < 4; ++mt)
                    #pragma unroll
                    for (int j = 0; j < 4; ++j) {
                        int tok = mt * 16 + g * 4 + j;
                        if (tok < TOK) {
                            int ti = tok / WIN, tj = tok - (tok / WIN) * WIN;
                            int ph = wi * WIN + ti + SHIFT; if (ph >= HH) ph -= HH;
                            int pw = wj * WIN + tj + SHIFT; if (pw >= HH) pw -= HH;
                            size_t gi = bbase + (size_t)(ph * HH + pw) * CH + ncol;
                            out[gi] = x[gi] + acc[mt][j] + bias;
                        }
                    }
            }
        }
    }
}

__global__ __launch_bounds__(256) void swin_mlp(
    float* __restrict__ out,
    const float* __restrict__ n2w, const float* __restrict__ n2b,
    const __hip_bfloat16* __restrict__ w1, const float* __restrict__ b1,
    const __hip_bfloat16* __restrict__ w2, const float* __restrict__ b2)
{
    __shared__ __align__(16) __hip_bfloat16 XL2[64][104];
    __shared__ __align__(16) __hip_bfloat16 Hs[64][200];   // one 192-col chunk of MLP hidden

    const int tid = threadIdx.x;
    const int lane = tid & 63, w = tid >> 6;
    const int lr = lane & 15, g = lane >> 4, k0 = g * 8;
    const size_t base = (size_t)blockIdx.x * 64 * CH;

    // ---- LN2 (4 threads/row) ----
    {
        int r = tid >> 2, p = tid & 3;
        const float4* xr = (const float4*)(out + base + (size_t)r * CH + p * 24);
        float v[24]; float s = 0.f, s2 = 0.f;
        #pragma unroll
        for (int i = 0; i < 6; ++i) {
            float4 f = xr[i];
            v[4*i] = f.x; v[4*i+1] = f.y; v[4*i+2] = f.z; v[4*i+3] = f.w;
        }
        #pragma unroll
        for (int i = 0; i < 24; ++i) { s += v[i]; s2 += v[i] * v[i]; }
        s  += __shfl_xor(s, 1);  s  += __shfl_xor(s, 2);
        s2 += __shfl_xor(s2, 1); s2 += __shfl_xor(s2, 2);
        float mu = s * (1.f / CH);
        float rstd = rsqrtf(s2 * (1.f / CH) - mu * mu + 1e-5f);
        #pragma unroll
        for (int i = 0; i < 24; ++i) {
            int c = p * 24 + i;
            XL2[r][c] = __float2bfloat16((v[i] - mu) * rstd * n2w[c] + n2b[c]);
        }
    }
    __syncthreads();

    // ---- fc1/fc2 over 2 K-chunks of 192; all cross-wave handoffs via syncthreads ----
    bf16x8 A[4][3];
    #pragma unroll
    for (int mt = 0; mt < 4; ++mt)
        #pragma unroll
        for (int ks = 0; ks < 3; ++ks)
            A[mt][ks] = ldfrag(&XL2[mt * 16 + lr][ks * 32 + k0]);

    const int mh = w & 1, nh = w >> 1;
    f32x4 acc2[3][2];
    #pragma unroll
    for (int nt = 0; nt < 3; ++nt)
        #pragma unroll
        for (int mi = 0; mi < 2; ++mi) acc2[nt][mi] = (f32x4){0.f, 0.f, 0.f, 0.f};

    #pragma unroll
    for (int c = 0; c < 2; ++c) {
        // fc1 + sigmoid-GELU: 12 local n-tiles, wave w does nl = w, w+4, w+8
        #pragma unroll
        for (int nn = 0; nn < 3; ++nn) {
            int nl = w + 4 * nn;
            int ncol = c * 192 + nl * 16 + lr;          // global fc1 output row
            const __hip_bfloat16* wb = w1 + ncol * CH + k0;
            f32x4 acc[4];
            #pragma unroll
            for (int mt = 0; mt < 4; ++mt) acc[mt] = (f32x4){0.f, 0.f, 0.f, 0.f};
            #pragma unroll
            for (int ks = 0; ks < 3; ++ks) {
                bf16x8 bf = ldfrag(wb + ks * 32);
                #pragma unroll
                for (int mt = 0; mt < 4; ++mt) acc[mt] = MFMA(A[mt][ks], bf, acc[mt]);
            }
            float bias = b1[ncol];
            #pragma unroll
            for (int mt = 0; mt < 4; ++mt)
                #pragma unroll
                for (int j = 0; j < 4; ++j) {
                    float v = acc[mt][j] + bias;
                    float ge = v / (1.f + __expf(-1.702f * v));
                    Hs[mt * 16 + g * 4 + j][nl * 16 + lr] = __float2bfloat16(ge);
                }
        }
        __syncthreads();   // fc1 chunk visible to all waves
        // fc2 partial over this chunk's K=192: 2x2 (M-half x N-half) wave split
        #pragma unroll
        for (int k = 0; k < 6; ++k) {
            bf16x8 a0 = ldfrag(&Hs[mh * 32 + lr][k * 32 + k0]);
            bf16x8 a1 = ldfrag(&Hs[mh * 32 + 16 + lr][k * 32 + k0]);
            #pragma unroll
            for (int nt = 0; nt < 3; ++nt) {
                bf16x8 bf = ldfrag(w2 + (nh * 48 + nt * 16 + lr) * MLPH + c * 192 + k * 32 + k0);
                acc2[nt][0] = MFMA(a0, bf, acc2[nt][0]);
                acc2[nt][1] = MFMA(a1, bf, acc2[nt][1]);
            }
        }
        __syncthreads();   // fc2 reads done before next chunk's fc1 overwrites Hs
    }

    // ---- epilogue: residual RMW ----
    #pragma unroll
    for (int nt = 0; nt < 3; ++nt) {
        int col = nh * 48 + nt * 16 + lr;
        float bias = b2[col];
        #pragma unroll
        for (int mi = 0; mi < 2; ++mi)
            #pragma unroll
            for (int j = 0; j < 4; ++j) {
                int tok = mh * 32 + mi * 16 + g * 4 + j;
                size_t gi = base + (size_t)tok * CH + col;
                out[gi] += acc2[nt][mi][j] + bias;
            }
    }
}

extern "C" void kernel_launch(void* const* d_in, const int* in_sizes, int n_in,
                              void* d_out, int out_size, void* d_ws, size_t ws_size,
                              hipStream_t stream) {
    const float* x     = (const float*)d_in[0];
    const float* n1w   = (const float*)d_in[1];
    const float* n1b   = (const float*)d_in[2];
    const float* qkvw  = (const float*)d_in[3];
    const float* qkvb  = (const float*)d_in[4];
    const float* relb  = (const float*)d_in[5];
    const float* projw = (const float*)d_in[6];
    const float* projb = (const float*)d_in[7];
    const float* n2w   = (const float*)d_in[8];
    const float* n2b   = (const float*)d_in[9];
    const float* fc1w  = (const float*)d_in[10];
    const float* fc1b  = (const float*)d_in[11];
    const float* fc2w  = (const float*)d_in[12];
    const float* fc2b  = (const float*)d_in[13];
    float* out = (float*)d_out;

    __hip_bfloat16* wbf = (__hip_bfloat16*)d_ws;
    float* btab = (float*)((char*)d_ws + 221184);
    const __hip_bfloat16* wqkv  = wbf;
    const __hip_bfloat16* wproj = wbf + 27648;
    const __hip_bfloat16* wfc1  = wbf + 36864;
    const __hip_bfloat16* wfc2  = wbf + 73728;

    prep<<<624, 256, 0, stream>>>(qkvw, projw, fc1w, fc2w, relb, wbf, btab);
    swin_attn<<<BATCH * 64, 256, 0, stream>>>(
        x, n1w, n1b, wqkv, qkvb, btab, wproj, projb, out);
    swin_mlp<<<(BATCH * HH * HH) / 64, 256, 0, stream>>>(
        out, n2w, n2b, wfc1, fc1b, wfc2, fc2b);
}